// Round 1
// 511.733 us; speedup vs baseline: 1.0360x; 1.0360x over previous
//
#include <hip/hip_runtime.h>
#include <cstdint>
#include <cstddef>

// out[n, r*256+c] = sum_{e,i} x[n, cell(r,e)*64+i] * v[e,i,r,c] + b[r*256+c]
// 49 independent (8192x192)@(192x256) GEMMs. bf16 MFMA, fp32 accumulate.
// R3: wt (4.8 MB) and xb (28.3 MB) are L2/L3-resident -> LDS staging was pure
// overhead (6x syncthreads+vmcnt(0) drains per block at 2 waves/SIMD).
// New tic_gemm: ZERO LDS, ZERO barriers. B fragments load directly from a
// GEMM-native wt2[r][kc][quad][col][8k] layout (256B-coalesced), double-
// buffered A/B fragment registers, fully unrolled K-loop, free-running waves.

#define XCOLS   1728      // 27*64
#define ROWS_W  49
#define KTOT    192       // 3*64
#define OUTW    12544     // 49*256
#define XELEMS  (8192 * XCOLS)

typedef __attribute__((ext_vector_type(8))) short short8;
typedef __attribute__((ext_vector_type(4))) float f32x4;

struct CellTab { int c[ROWS_W][3]; };

// Faithful constexpr port of init_wincon_matrix(): cells[r][e] = board cell of
// the e-th put() for column r (step cycles 0,1,2 within each column).
constexpr CellTab make_cells() {
    CellTab t{};
    int step = 0, col = 0;
    int x = 0, y = 0, z = 0;
#define PUT() do { t.c[col][step] = x + 3*y + 9*z; step = (step + 1) % 3; } while (0)
    for (x = 0; x < 3; ++x) {
        for (y = 0; y < 3; ++y) {
            for (z = 0; z < 3; ++z) PUT();
            ++col;
        }
        for (z = 0; z < 3; ++z) {
            for (y = 0; y < 3; ++y) PUT();
            ++col;
        }
        for (y = 0; y < 3; ++y) { z = y; PUT(); }
        ++col;
        for (y = 0; y < 3; ++y) { z = 2 - y; PUT(); }
        ++col;
    }
    for (z = 0; z < 3; ++z) {
        for (y = 0; y < 3; ++y) {
            for (x = 0; x < 3; ++x) PUT();
            ++col;
        }
        for (y = 0; y < 3; ++y) { x = y; PUT(); }
        ++col;
        for (y = 0; y < 3; ++y) { x = 2 - y; PUT(); }
        ++col;
    }
    for (y = 0; y < 3; ++y) {
        for (z = 0; z < 3; ++z) { x = z; PUT(); }
        ++col;
        for (z = 0; z < 3; ++z) { x = 2 - z; PUT(); }
        ++col;
    }
    for (x = 0; x < 3; ++x) { y = x; z = x; PUT(); }
    ++col;
    for (x = 0; x < 3; ++x) { y = 2 - x; z = 2 - x; PUT(); }
    ++col;
    for (x = 0; x < 3; ++x) { y = x; z = 2 - x; PUT(); }
    ++col;
    for (x = 0; x < 3; ++x) { z = x; y = 2 - x; PUT(); }
    ++col;
#undef PUT
    return t;
}

__constant__ CellTab CELLS = make_cells();

__device__ __forceinline__ unsigned short f2bf(float f) {
    union { float f; unsigned u; } a; a.f = f;
    unsigned u = a.u;
    return (unsigned short)((u + 0x7fffu + ((u >> 16) & 1u)) >> 16);  // RNE
}

// ---------------------------------------------------------------------------
// Prepass A: xb[n][col] = bf16(x[n][col]), row-major. 8 elems/thread.
// ---------------------------------------------------------------------------
__global__ __launch_bounds__(256) void x_prepass(const float* __restrict__ x,
                                                 unsigned short* __restrict__ xb) {
    const size_t i8 = (size_t)(blockIdx.x * 256 + threadIdx.x) * 8;
    const float4 a0 = *(const float4*)(x + i8);
    const float4 a1 = *(const float4*)(x + i8 + 4);
    short8 s;
    s[0] = (short)f2bf(a0.x); s[1] = (short)f2bf(a0.y);
    s[2] = (short)f2bf(a0.z); s[3] = (short)f2bf(a0.w);
    s[4] = (short)f2bf(a1.x); s[5] = (short)f2bf(a1.y);
    s[6] = (short)f2bf(a1.z); s[7] = (short)f2bf(a1.w);
    *(short8*)(xb + i8) = s;
}

// ---------------------------------------------------------------------------
// Prepass B: wt2[r][kc][q][c][j] (bf16) = v[k][r][c], k = kc*32 + q*8 + j.
// This is exactly the per-lane B-fragment layout of the GEMM: a wave's B-frag
// load for (kc, nt) is 4 x 256B fully-contiguous segments.
// Reads of v are coalesced (1 KB per (q,j) across the 256 threads).
// ---------------------------------------------------------------------------
__global__ __launch_bounds__(256) void wt_prepass(const float* __restrict__ v,
                                                  unsigned short* __restrict__ wt) {
    const int kc = blockIdx.x;   // 0..5
    const int r  = blockIdx.y;   // 0..48
    const int c  = threadIdx.x;  // 0..255
#pragma unroll
    for (int q = 0; q < 4; ++q) {
        short8 s;
#pragma unroll
        for (int j = 0; j < 8; ++j) {
            const int k = kc * 32 + q * 8 + j;
            s[j] = (short)f2bf(v[(size_t)k * OUTW + r * 256 + c]);
        }
        *(short8*)(wt + ((((size_t)r * 6 + kc) * 4 + q) * 256 + c) * 8) = s;
    }
}

// ---------------------------------------------------------------------------
// Main GEMM. Block = one (r, 128-row m-tile) x ALL 256 cols. 256 thr / 4 waves.
// Wave (wh = wave>>1, half = wave&1) owns rows [wh*64, +64) x cols
// [half*128, +128): acc = 4 mt x 8 nt x f32x4 = 128 VGPR.
// NO LDS, NO barriers: wt (4.8 MB) + xb m-panels are L2/L3-resident, so each
// wave streams fragments directly from cache:
//   B-frag (kc,nt): wt2[r][kc][quad][half*128+nt*16+l15][0..7]  (k-contiguous,
//     per-instruction 4 x 256B coalesced segments)
//   A-frag (kc,mt): xb[row][cell*64 + h*32 + quad*8 .. +7]      (16 x 64B segs)
// Double-buffered afr/bfr registers; fully unrolled kc-loop pipelines loads of
// kc+1 under the 32 MFMAs of kc. Epilogue stores overlap the co-resident
// block's compute (2 blocks/CU, launch_bounds(256,2)).
// Grid m-major (consecutive bids share m-tile -> x panel shared in L2/L3).
// ---------------------------------------------------------------------------
__global__ __launch_bounds__(256, 2) void tic_gemm(
    const unsigned short* __restrict__ xb,
    const unsigned short* __restrict__ wt,
    const float* __restrict__ bias,
    float* __restrict__ out)
{
    const int bid   = blockIdx.x;
    const int m     = bid / 49;
    const int r     = bid % 49;
    const int mbase = m * 128;

    const int t    = threadIdx.x;
    const int wave = t >> 6;
    const int lane = t & 63;
    const int l15  = lane & 15;
    const int quad = lane >> 4;
    const int half = wave & 1;   // column half (0: cols 0-127, 1: 128-255)
    const int wh   = wave >> 1;  // row half (0: rows 0-63, 1: 64-127)

    const int cells[3] = { CELLS.c[r][0], CELLS.c[r][1], CELLS.c[r][2] };

    // acc init = bias (per-column, identical for all rows)
    f32x4 acc[4][8];
#pragma unroll
    for (int nt = 0; nt < 8; ++nt) {
        const float bv = bias[r * 256 + half * 128 + nt * 16 + l15];
        f32x4 a; a[0] = bv; a[1] = bv; a[2] = bv; a[3] = bv;
#pragma unroll
        for (int mt = 0; mt < 4; ++mt) acc[mt][nt] = a;
    }

    // per-lane B base: wt2 element (((r*6+kc)*4+quad)*256 + half*128 + l15)*8
    // kc advances by 4*256*8 = 8192 elems; nt advances by 16*8 = 128 elems.
    const unsigned short* wbase =
        wt + ((size_t)(r * 24 + quad) * 256 + half * 128 + l15) * 8;

    short8 afr[2][4];  // [kc-parity][mt] -- A frags straight from xb
    short8 bfr[2][8];  // [kc-parity][nt] -- B frags straight from wt2

    auto loadA = [&](int kc, int p) {
        const int e = kc >> 1, h = kc & 1;
        const int colb = cells[e] * 64 + h * 32 + quad * 8;
#pragma unroll
        for (int mt = 0; mt < 4; ++mt) {
            const int row = mbase + wh * 64 + mt * 16 + l15;
            afr[p][mt] = *(const short8*)(xb + (size_t)row * XCOLS + colb);
        }
    };
    auto loadB = [&](int kc, int p) {
        const unsigned short* src = wbase + (size_t)kc * 8192;
#pragma unroll
        for (int nt = 0; nt < 8; ++nt)
            bfr[p][nt] = *(const short8*)(src + nt * 128);
    };

    loadA(0, 0);
    loadB(0, 0);

#pragma unroll
    for (int kc = 0; kc < 6; ++kc) {
        const int p = kc & 1;
        if (kc < 5) {
            loadB(kc + 1, p ^ 1);
            loadA(kc + 1, p ^ 1);
        }
#pragma unroll
        for (int nt = 0; nt < 8; ++nt) {
#pragma unroll
            for (int mt = 0; mt < 4; ++mt)
                acc[mt][nt] = __builtin_amdgcn_mfma_f32_16x16x32_bf16(
                    afr[p][mt], bfr[p][nt], acc[mt][nt], 0, 0, 0);
        }
    }

    // Epilogue: C/D layout col=lane&15, row=quad*4+reg  [m89-verified]
    // Each 16-lane group writes one aligned 64-B line per (mt,v4,nt).
#pragma unroll
    for (int mt = 0; mt < 4; ++mt) {
#pragma unroll
        for (int v4 = 0; v4 < 4; ++v4) {
            const int row = mbase + wh * 64 + mt * 16 + quad * 4 + v4;
            float* orow = out + (size_t)row * OUTW + r * 256 + half * 128;
#pragma unroll
            for (int nt = 0; nt < 8; ++nt)
                orow[nt * 16 + l15] = acc[mt][nt][v4];
        }
    }
}

extern "C" void kernel_launch(void* const* d_in, const int* in_sizes, int n_in,
                              void* d_out, int out_size, void* d_ws, size_t ws_size,
                              hipStream_t stream) {
    const float* x  = (const float*)d_in[0];   // (8192, 1728) fp32
    const float* v  = (const float*)d_in[1];   // (3, 64, 49, 256) fp32
    const float* b  = (const float*)d_in[2];   // (12544,) fp32
    float* out = (float*)d_out;                // (8192, 12544) fp32

    unsigned short* xb = (unsigned short*)d_ws;          // 28.3 MB bf16 x
    unsigned short* wt = xb + (size_t)XELEMS;            // 4.8 MB bf16 wt2

    x_prepass<<<dim3(XELEMS / (256 * 8)), dim3(256), 0, stream>>>(x, xb);
    wt_prepass<<<dim3(6, 49), dim3(256), 0, stream>>>(v, wt);
    tic_gemm<<<dim3(64 * 49), dim3(256), 0, stream>>>(xb, wt, b, out);
}